// Round 1
// baseline (107.308 us; speedup 1.0000x reference)
//
#include <hip/hip_runtime.h>
#include <math.h>

#define CAPV 2560

__device__ __forceinline__ float wave_sum64(float v) {
#pragma unroll
  for (int o = 32; o; o >>= 1) v += __shfl_xor(v, o, 64);
  return v;
}

__device__ __forceinline__ float silu_f(float t) {
  return t / (1.f + __expf(-t));
}

// ---------------- routing: 1 block, 256 threads (one per patch) ----------------
__global__ __launch_bounds__(256) void routing_kernel(
    const float* __restrict__ gate_w, const float* __restrict__ gate_b,
    int* __restrict__ route_e, float* __restrict__ route_gate,
    int* __restrict__ route_cpre, int* __restrict__ route_Ce,
    float* __restrict__ d_scalars) {
  const int p = threadIdx.x;            // patch index 0..255
  const int lane = p & 63, wv = p >> 6; // 4 waves
  const int hp = p >> 4, wp = p & 15;

  // pooled fourier features (mean over 8x8 patch; y-channels depend on rows only)
  float pool[18];
  {
    float my = 0.f, mx_ = 0.f;
    float msy[4] = {0, 0, 0, 0}, mcy[4] = {0, 0, 0, 0};
    float msx[4] = {0, 0, 0, 0}, mcx[4] = {0, 0, 0, 0};
#pragma unroll
    for (int r = 0; r < 8; ++r) {
      float yv = -1.f + (2.f / 127.f) * (float)(hp * 8 + r);
      float xv = -1.f + (2.f / 127.f) * (float)(wp * 8 + r);
      my += yv; mx_ += xv;
#pragma unroll
      for (int k = 0; k < 4; ++k) {
        float fr = 3.14159265358979323846f * (float)(1 << k);
        msy[k] += sinf(fr * yv); mcy[k] += cosf(fr * yv);
        msx[k] += sinf(fr * xv); mcx[k] += cosf(fr * xv);
      }
    }
    pool[0] = my * 0.125f; pool[1] = mx_ * 0.125f;
#pragma unroll
    for (int k = 0; k < 4; ++k) {
      pool[2 + 4 * k] = msy[k] * 0.125f;
      pool[3 + 4 * k] = mcy[k] * 0.125f;
      pool[4 + 4 * k] = msx[k] * 0.125f;
      pool[5 + 4 * k] = mcx[k] * 0.125f;
    }
  }

  __shared__ float sWP[4][8];   // per-wave prob sums
  __shared__ float sWZ[4];      // per-wave lse^2 sums
  __shared__ int sWCnt[4][8];   // per-wave expert counts
  __shared__ float sMeanP[8], sFrac[8];
  __shared__ float sAcc[2];
  if (p == 0) { sAcc[0] = 0.f; sAcc[1] = 0.f; }

  for (int l = 0; l < 2; ++l) {
    float logit[8];
#pragma unroll
    for (int e = 0; e < 8; ++e) logit[e] = gate_b[l * 8 + e];
#pragma unroll
    for (int c = 0; c < 18; ++c) {
      float pl = pool[c];
#pragma unroll
      for (int e = 0; e < 8; ++e)
        logit[e] = fmaf(pl, gate_w[(l * 18 + c) * 8 + e], logit[e]);
    }
    float mxv = logit[0]; int em = 0;
#pragma unroll
    for (int e = 1; e < 8; ++e)
      if (logit[e] > mxv) { mxv = logit[e]; em = e; }
    float pr[8]; float se = 0.f;
#pragma unroll
    for (int e = 0; e < 8; ++e) { pr[e] = expf(logit[e] - mxv); se += pr[e]; }
    float inv = 1.f / se;
#pragma unroll
    for (int e = 0; e < 8; ++e) pr[e] *= inv;
    float lse = mxv + logf(se);
    float gate_val = inv; // prob at argmax = exp(0)/se

    // expert membership masks (ballot) -> prefix counts
    unsigned long long meq[8];
#pragma unroll
    for (int e = 0; e < 8; ++e) meq[e] = __ballot(em == e);
    unsigned long long mm = meq[0];
#pragma unroll
    for (int e = 1; e < 8; ++e) mm = (em == e) ? meq[e] : mm;
    unsigned long long below = (2ull << lane) - 1ull; // inclusive
    int cpre_w = (int)__popcll(mm & below);
    if (lane < 8) {
      unsigned long long t = meq[0];
#pragma unroll
      for (int e = 1; e < 8; ++e) t = (lane == e) ? meq[e] : t;
      sWCnt[wv][lane] = (int)__popcll(t);
    }
    float z2 = wave_sum64(lse * lse);
    if (lane == 0) sWZ[wv] = z2;
#pragma unroll
    for (int e = 0; e < 8; ++e) {
      float s = wave_sum64(pr[e]);
      if (lane == 0) sWP[wv][e] = s;
    }
    __syncthreads();

    int cpre = cpre_w;
#pragma unroll
    for (int w2 = 0; w2 < 4; ++w2)
      if (w2 < wv) cpre += sWCnt[w2][em];

    route_e[l * 256 + p] = em;
    route_gate[l * 256 + p] = gate_val;
    route_cpre[l * 256 + p] = cpre;

    if (p < 8) {
      int ce = sWCnt[0][p] + sWCnt[1][p] + sWCnt[2][p] + sWCnt[3][p];
      route_Ce[l * 8 + p] = ce;
      int kept = 0;
      for (int bb = 0; bb < 64; ++bb) {
        int r = CAPV - bb * ce;
        r = r < 0 ? 0 : r;
        kept += (r < ce ? r : ce);
      }
      sFrac[p] = (float)kept * (1.f / 16384.f);
      sMeanP[p] = (sWP[0][p] + sWP[1][p] + sWP[2][p] + sWP[3][p]) * (1.f / 256.f);
    }
    __syncthreads();
    if (p == 0) {
      float s = 0.f;
#pragma unroll
      for (int e = 0; e < 8; ++e) s += sMeanP[e] * sFrac[e];
      sAcc[1] += 8.f * s;
      sAcc[0] += (sWZ[0] + sWZ[1] + sWZ[2] + sWZ[3]) * (1.f / 256.f);
    }
    __syncthreads();
  }
  if (p == 0) { d_scalars[0] = sAcc[0]; d_scalars[1] = sAcc[1]; }
}

// ---------------- token kernel: one token per 64-thread block ----------------
__global__ __launch_bounds__(64) void token_kernel(
    const float* __restrict__ X,
    const float* __restrict__ stem_w, const float* __restrict__ stem_sc,
    const float* __restrict__ stem_bi,
    const float* __restrict__ exp_w, const float* __restrict__ exp_b,
    const float* __restrict__ gn_s, const float* __restrict__ gn_b,
    const int* __restrict__ route_e, const float* __restrict__ route_gate,
    const int* __restrict__ route_cpre, const int* __restrict__ route_Ce,
    float* __restrict__ tok_sums) {
  const int n = blockIdx.x;
  const int b = n >> 8, p = n & 255;
  const int hp = p >> 4, wp = p & 15;
  const int tid = threadIdx.x;
  const int y = tid >> 3, x = tid & 7;

  __shared__ float sX[3][10][10];  // stem input halo
  __shared__ float sT[8][10][10];  // token buffer, zero-padded border

  // load X halo with zero padding at image edges
  const int gy0 = hp * 8 - 1, gx0 = wp * 8 - 1;
  for (int i = tid; i < 300; i += 64) {
    int ci = i / 100, rem = i % 100;
    int r = rem / 10, c = rem % 10;
    int gy = gy0 + r, gx = gx0 + c;
    float v = 0.f;
    if (gy >= 0 && gy < 128 && gx >= 0 && gx < 128)
      v = X[((b * 3 + ci) * 128 + gy) * 128 + gx];
    sX[ci][r][c] = v;
  }
  // zero the border of sT once; interior is always overwritten
  for (int i = tid; i < 800; i += 64) {
    int rem = i % 100;
    int r = rem / 10, c = rem % 10;
    if (r == 0 || r == 9 || c == 0 || c == 9) ((float*)sT)[i] = 0.f;
  }
  __syncthreads();

  // stem conv 3->8 + affine + SiLU (weights are uniform -> scalar loads)
  {
    float acc[8];
#pragma unroll
    for (int co = 0; co < 8; ++co) acc[co] = 0.f;
#pragma unroll
    for (int ci = 0; ci < 3; ++ci) {
      float v[9];
#pragma unroll
      for (int dy = 0; dy < 3; ++dy)
#pragma unroll
        for (int dx = 0; dx < 3; ++dx)
          v[dy * 3 + dx] = sX[ci][y + dy][x + dx];
#pragma unroll
      for (int co = 0; co < 8; ++co)
#pragma unroll
        for (int k = 0; k < 9; ++k)
          acc[co] = fmaf(stem_w[(co * 3 + ci) * 9 + k], v[k], acc[co]);
    }
#pragma unroll
    for (int co = 0; co < 8; ++co) {
      float t = fmaf(acc[co], stem_sc[co], stem_bi[co]);
      sT[co][y + 1][x + 1] = silu_f(t);
    }
  }
  __syncthreads();

  float a[8];
#pragma unroll
  for (int l = 0; l < 2; ++l) {
    int e = route_e[l * 256 + p];
    e = __builtin_amdgcn_readfirstlane(e);  // block-uniform -> enables s_load of weights
    float gp = route_gate[l * 256 + p];
    int cpre = route_cpre[l * 256 + p];
    int Ce = route_Ce[l * 8 + e];
    float gate = (b * Ce + cpre <= CAPV) ? gp : 0.f;
    const float* __restrict__ w = exp_w + (size_t)(l * 8 + e) * 576;
    const float* __restrict__ wb = exp_b + (size_t)(l * 8 + e) * 8;

#pragma unroll
    for (int co = 0; co < 8; ++co) a[co] = wb[co];
#pragma unroll
    for (int ci = 0; ci < 8; ++ci) {
      float v[9];
#pragma unroll
      for (int dy = 0; dy < 3; ++dy)
#pragma unroll
        for (int dx = 0; dx < 3; ++dx)
          v[dy * 3 + dx] = sT[ci][y + dy][x + dx];
#pragma unroll
      for (int co = 0; co < 8; ++co)
#pragma unroll
        for (int k = 0; k < 9; ++k)
          a[co] = fmaf(w[(co * 8 + ci) * 9 + k], v[k], a[co]);
    }
#pragma unroll
    for (int co = 0; co < 8; ++co) a[co] = silu_f(a[co]) * gate;

    if (l == 0) {
      // per-token GroupNorm (4 groups of 2 channels x 64 spatial = 128 vals)
      float mu[4], invs[4];
#pragma unroll
      for (int g = 0; g < 4; ++g) {
        float s = a[2 * g] + a[2 * g + 1];
        float q = a[2 * g] * a[2 * g] + a[2 * g + 1] * a[2 * g + 1];
        s = wave_sum64(s);
        q = wave_sum64(q);
        float m = s * (1.f / 128.f);
        float var = q * (1.f / 128.f) - m * m;
        mu[g] = m;
        invs[g] = rsqrtf(var + 1e-5f);
      }
      __syncthreads();  // conv reads of sT complete before overwrite
#pragma unroll
      for (int co = 0; co < 8; ++co) {
        int g = co >> 1;
        sT[co][y + 1][x + 1] = fmaf((a[co] - mu[g]) * invs[g], gn_s[co], gn_b[co]);
      }
      __syncthreads();
    }
  }

  // per-token partial sums for image-level GN + pooling:
  // 8 channel sums + 4 group sum-of-squares
  float red[12];
#pragma unroll
  for (int co = 0; co < 8; ++co) red[co] = a[co];
#pragma unroll
  for (int g = 0; g < 4; ++g)
    red[8 + g] = a[2 * g] * a[2 * g] + a[2 * g + 1] * a[2 * g + 1];
#pragma unroll
  for (int j = 0; j < 12; ++j) red[j] = wave_sum64(red[j]);
  if (tid == 0) {
#pragma unroll
    for (int j = 0; j < 12; ++j) tok_sums[(size_t)n * 12 + j] = red[j];
  }
}

// ---------------- finish: per-image GN-folded pooling + MLP head ----------------
__global__ __launch_bounds__(128) void finish_kernel(
    const float* __restrict__ tok_sums,
    const float* __restrict__ gn_s, const float* __restrict__ gn_b,
    const float* __restrict__ w1, const float* __restrict__ b1,
    const float* __restrict__ w2, const float* __restrict__ b2,
    float* __restrict__ out) {
  const int b = blockIdx.x;
  const int tid = threadIdx.x;
  const int lane = tid & 63, wv = tid >> 6;
  __shared__ float sPart[2][12];
  __shared__ float sSum[12];
  __shared__ float sPooled[8];
  __shared__ float sH1[32];

  float l0[12];
#pragma unroll
  for (int j = 0; j < 12; ++j) l0[j] = 0.f;
  for (int pp = tid; pp < 256; pp += 128) {
    const float4* s4 = (const float4*)(tok_sums + (size_t)(b * 256 + pp) * 12);
    float4 a0 = s4[0], a1 = s4[1], a2 = s4[2];
    l0[0] += a0.x; l0[1] += a0.y; l0[2] += a0.z; l0[3] += a0.w;
    l0[4] += a1.x; l0[5] += a1.y; l0[6] += a1.z; l0[7] += a1.w;
    l0[8] += a2.x; l0[9] += a2.y; l0[10] += a2.z; l0[11] += a2.w;
  }
#pragma unroll
  for (int j = 0; j < 12; ++j) l0[j] = wave_sum64(l0[j]);
  if (lane == 0) {
#pragma unroll
    for (int j = 0; j < 12; ++j) sPart[wv][j] = l0[j];
  }
  __syncthreads();
  if (tid < 12) sSum[tid] = sPart[0][tid] + sPart[1][tid];
  __syncthreads();
  if (tid < 8) {
    int g = tid >> 1;
    float mean_c = sSum[tid] * (1.f / 16384.f);
    float mug = (sSum[2 * g] + sSum[2 * g + 1]) * (1.f / 32768.f);
    float var = sSum[8 + g] * (1.f / 32768.f) - mug * mug;
    float inv = rsqrtf(var + 1e-5f);
    sPooled[tid] = fmaf((mean_c - mug) * inv, gn_s[8 + tid], gn_b[8 + tid]);
  }
  __syncthreads();
  if (tid < 32) {
    float h = b1[tid];
#pragma unroll
    for (int c = 0; c < 8; ++c) h = fmaf(sPooled[c], w1[c * 32 + tid], h);
    float t = 0.7978845608028654f * fmaf(0.044715f * h * h, h, h);
    sH1[tid] = 0.5f * h * (1.f + tanhf(t));
  }
  __syncthreads();
  if (tid < 100) {
    float o = b2[tid];
#pragma unroll
    for (int j = 0; j < 32; ++j) o = fmaf(sH1[j], w2[j * 100 + tid], o);
    out[b * 100 + tid] = o;
  }
}

extern "C" void kernel_launch(void* const* d_in, const int* in_sizes, int n_in,
                              void* d_out, int out_size, void* d_ws, size_t ws_size,
                              hipStream_t stream) {
  const float* X       = (const float*)d_in[0];
  const float* stem_w  = (const float*)d_in[1];
  const float* stem_sc = (const float*)d_in[2];
  const float* stem_bi = (const float*)d_in[3];
  const float* gate_w  = (const float*)d_in[4];
  const float* gate_b  = (const float*)d_in[5];
  const float* exp_w   = (const float*)d_in[6];
  const float* exp_b   = (const float*)d_in[7];
  const float* gn_s    = (const float*)d_in[8];
  const float* gn_b    = (const float*)d_in[9];
  const float* w1      = (const float*)d_in[10];
  const float* b1      = (const float*)d_in[11];
  const float* w2      = (const float*)d_in[12];
  const float* b2      = (const float*)d_in[13];
  float* out = (float*)d_out;

  char* ws = (char*)d_ws;
  int* route_e      = (int*)(ws + 0);          // 512 ints
  int* route_cpre   = (int*)(ws + 2048);       // 512 ints
  int* route_Ce     = (int*)(ws + 4096);       // 16 ints
  float* route_gate = (float*)(ws + 4096 + 64);// 512 floats
  float* tok_sums   = (float*)(ws + 8192);     // 16384*12 floats (~768 KiB)

  routing_kernel<<<1, 256, 0, stream>>>(gate_w, gate_b, route_e, route_gate,
                                        route_cpre, route_Ce, out + 6400);
  token_kernel<<<16384, 64, 0, stream>>>(X, stem_w, stem_sc, stem_bi, exp_w,
                                         exp_b, gn_s, gn_b, route_e, route_gate,
                                         route_cpre, route_Ce, tok_sums);
  finish_kernel<<<64, 128, 0, stream>>>(tok_sums, gn_s, gn_b, w1, b1, w2, b2,
                                        out);
}